// Round 13
// baseline (193.546 us; speedup 1.0000x reference)
//
#include <hip/hip_runtime.h>
#include <hip/hip_bf16.h>
#include <math.h>

#define DEV __device__ __forceinline__

typedef __attribute__((ext_vector_type(4))) float f32x4;
typedef __attribute__((ext_vector_type(16))) float f32x16;
typedef __attribute__((ext_vector_type(8))) short bf16x8;     // 8 bf16 in 4 VGPRs (MFMA frag)
typedef __attribute__((ext_vector_type(8))) unsigned short u16x8;
typedef unsigned short u16;
typedef unsigned int u32;

DEV u16 f2bf(float f) {
  union { float f; u32 u; } v; v.f = f;
  u32 r = v.u + 0x7fffu + ((v.u >> 16) & 1u);
  return (u16)(r >> 16);
}
DEV float bf2f(u16 h) {
  union { u32 u; float f; } v; v.u = ((u32)h) << 16;
  return v.f;
}
DEV float bfel(bf16x8 v, int e) {
  union { bf16x8 b; u16x8 u; } x; x.b = v; return bf2f(x.u[e]);
}

DEV void gl_lds16(const u16* g, u16* s) {
  __builtin_amdgcn_global_load_lds((const __attribute__((address_space(1))) void*)g,
                                   (__attribute__((address_space(3))) void*)s, 16, 0, 0);
}

// raw barrier (no implicit vmcnt drain), pinned against compiler motion
DEV void barrier_() {
  __builtin_amdgcn_sched_barrier(0);
  asm volatile("" ::: "memory");
  __builtin_amdgcn_s_barrier();
  asm volatile("" ::: "memory");
  __builtin_amdgcn_sched_barrier(0);
}

#define MFMA16(a, b, c) __builtin_amdgcn_mfma_f32_16x16x32_bf16((a), (b), (c), 0, 0, 0)
#define MFMA32(a, b, c) __builtin_amdgcn_mfma_f32_32x32x16_bf16((a), (b), (c), 0, 0, 0)

// ---------------------------------------------------------------------------
// Prep: cast src + weights to bf16; concat wq|wk|wv|wg -> Wcat (k scaled 0.125);
// concat biases bq|bk*0.125|bv|bg -> bcat.
// ---------------------------------------------------------------------------
DEV void cast8(const float* in, u16* out, float s) {
  f32x4 a = *(const f32x4*)in;
  f32x4 b = *(const f32x4*)(in + 4);
  u16x8 r;
  r[0] = f2bf(a[0] * s); r[1] = f2bf(a[1] * s); r[2] = f2bf(a[2] * s); r[3] = f2bf(a[3] * s);
  r[4] = f2bf(b[0] * s); r[5] = f2bf(b[1] * s); r[6] = f2bf(b[2] * s); r[7] = f2bf(b[3] * s);
  *(u16x8*)out = r;
}

__global__ __launch_bounds__(256) void prep_cast(
    const float* __restrict__ src, const float* __restrict__ wq, const float* __restrict__ wk,
    const float* __restrict__ wv, const float* __restrict__ wg, const float* __restrict__ wo,
    const float* __restrict__ fc1, const float* __restrict__ fc2,
    const float* __restrict__ bq, const float* __restrict__ bk,
    const float* __restrict__ bv, const float* __restrict__ bg,
    u16* __restrict__ src_bf, u16* __restrict__ Wcat, u16* __restrict__ wo_bf,
    u16* __restrict__ fc1_bf, u16* __restrict__ fc2_bf, float* __restrict__ bcat) {
  int u = blockIdx.x * 256 + threadIdx.x;
  if (u < 524288) {
    cast8(src + (size_t)u * 8, src_bf + (size_t)u * 8, 1.0f);
  } else if (u < 557056) {
    int v = u - 524288; cast8(wq + (size_t)v * 8, Wcat + (size_t)v * 8, 1.0f);
  } else if (u < 589824) {
    int v = u - 557056; cast8(wk + (size_t)v * 8, Wcat + 262144 + (size_t)v * 8, 0.125f);
  } else if (u < 622592) {
    int v = u - 589824; cast8(wv + (size_t)v * 8, Wcat + 524288 + (size_t)v * 8, 1.0f);
  } else if (u < 655360) {
    int v = u - 622592; cast8(wg + (size_t)v * 8, Wcat + 786432 + (size_t)v * 8, 1.0f);
  } else if (u < 688128) {
    int v = u - 655360; cast8(wo + (size_t)v * 8, wo_bf + (size_t)v * 8, 1.0f);
  } else if (u < 819200) {
    int v = u - 688128; cast8(fc1 + (size_t)v * 8, fc1_bf + (size_t)v * 8, 1.0f);
  } else if (u < 950272) {
    int v = u - 819200; cast8(fc2 + (size_t)v * 8, fc2_bf + (size_t)v * 8, 1.0f);
  } else if (u < 950528) {
    int v = u - 950272;
    #pragma unroll
    for (int e = 0; e < 8; e++) {
      int c = v * 8 + e;
      float val;
      if (c < 512)       val = bq[c];
      else if (c < 1024) val = bk[c - 512] * 0.125f;
      else if (c < 1536) val = bv[c - 1024];
      else               val = bg[c - 1536];
      bcat[c] = val;
    }
  }
}

// ---------------------------------------------------------------------------
// gemm_fat: C = A(MxK) @ W^T + bias, bf16 out. 256x256 tile, 512 thr (8 waves,
// 2Mx4N; wave = 128x64), BK=128, NT=K/128=4 FAT iterations, single-buffered
// 128KB LDS. Per iter: {STAGE 128KB; vmcnt(0); bar; 128 MFMA16/wave; lgkm0;
// bar}. Fewest possible barrier-iterations for this shape. Swizzle:
// chunk' = chunk ^ (row&15), source pre-swizzled (j-invariant).
// ---------------------------------------------------------------------------
template <int ACT>
__global__ __launch_bounds__(512) void gemm_fat(
    const u16* __restrict__ A, const u16* __restrict__ W, const float* __restrict__ bias,
    u16* __restrict__ Ob, int N, int K, int TN) {
  __shared__ __align__(16) u16 sm[65536];   // A[256][128] @0 | B[256][128] @32768
  const int t = threadIdx.x, l = t & 63;
  const int w = t >> 6, wm = w >> 2, wn = w & 3;
  const int lc = l & 15, lch = l >> 4;
  const int NT = K >> 7;

  const int orig = blockIdx.x;
  const int cpx = gridDim.x >> 3;
  const int sid = (orig & 7) * cpx + (orig >> 3);
  const int bm = (sid / TN) * 256, bn = (sid % TN) * 256;

  // staging: thread covers rows srow0 + j*32 (j=0..7), slot t&15.
  // content at slot s of row r must be chunk c = s ^ (r&15); (r&15) == (srow0&15)
  const int srow0 = t >> 4, slot = t & 15;
  const int soff = (slot ^ (srow0 & 15)) * 8;
  const u16* stA = A + (size_t)(bm + srow0) * K + soff;
  const u16* stB = W + (size_t)(bn + srow0) * K + soff;
  u16* dA = sm + srow0 * 128 + slot * 8;
  u16* dB = dA + 32768;

  f32x4 acc[8][4] = {};

  for (int tt = 0; tt < NT; ++tt) {
    const int kt = tt * 128;
    #pragma unroll
    for (int j = 0; j < 8; j++) {
      gl_lds16(stA + (size_t)(j * 32) * K + kt, dA + j * 4096);
      gl_lds16(stB + (size_t)(j * 32) * K + kt, dB + j * 4096);
    }
    asm volatile("s_waitcnt vmcnt(0)" ::: "memory");
    barrier_();
    #pragma unroll
    for (int ks = 0; ks < 4; ks++) {
      bf16x8 bfv[4];
      #pragma unroll
      for (int ni = 0; ni < 4; ni++) {
        const int r = wn * 64 + ni * 16 + lc;
        bfv[ni] = *(const bf16x8*)&sm[32768 + r * 128 + (((ks * 4 + lch) ^ (r & 15)) * 8)];
      }
      __builtin_amdgcn_s_setprio(1);
      #pragma unroll
      for (int mi = 0; mi < 8; mi++) {
        const int r = wm * 128 + mi * 16 + lc;
        bf16x8 af = *(const bf16x8*)&sm[r * 128 + (((ks * 4 + lch) ^ (r & 15)) * 8)];
        #pragma unroll
        for (int ni = 0; ni < 4; ni++)
          acc[mi][ni] = MFMA16(af, bfv[ni], acc[mi][ni]);
      }
      __builtin_amdgcn_s_setprio(0);
    }
    asm volatile("s_waitcnt lgkmcnt(0)" ::: "memory");
    barrier_();
  }

  // epilogue: bias (+gelu) -> swizzled LDS [256][256] -> coalesced 16B stores
  u16* osm = sm;
  #pragma unroll
  for (int ni = 0; ni < 4; ni++) {
    const int col = wn * 64 + ni * 16 + lc;
    const float bb = bias[bn + col];
    const int cch = col >> 3, clow = col & 7;
    #pragma unroll
    for (int mi = 0; mi < 8; mi++) {
      #pragma unroll
      for (int r = 0; r < 4; r++) {
        const int row = wm * 128 + mi * 16 + lch * 4 + r;
        float v = acc[mi][ni][r] + bb;
        if (ACT == 1) v = 0.5f * v * (1.0f + erff(v * 0.70710678118f));
        osm[row * 256 + ((cch ^ ((row & 7) << 2)) << 3) + clow] = f2bf(v);
      }
    }
  }
  __syncthreads();
  #pragma unroll
  for (int p = 0; p < 16; p++) {
    const int flat = p * 512 + t;
    const int row = flat >> 5, c = flat & 31;
    u16x8 y = *(const u16x8*)&osm[row * 256 + ((c ^ ((row & 7) << 2)) << 3)];
    *(u16x8*)&Ob[(size_t)(bm + row) * N + bn + c * 8] = y;
  }
}

// ---------------------------------------------------------------------------
// gemm_m64_ring: 64x128 tile, BK=32, 4-slot ring (48KB -> 3 blocks/CU),
// depth-3 prefetch (3 loads/iter: vmcnt 9/6/3/0). For N=512 GEMMs (wo, fc2).
// ---------------------------------------------------------------------------
template <int ACT>
__global__ __launch_bounds__(256) void gemm_m64_ring(
    const u16* __restrict__ A, const u16* __restrict__ W, const float* __restrict__ bias,
    u16* __restrict__ Ob, int N, int K, int TN) {
  __shared__ __align__(16) u16 sm[24576];   // 4 slots x (A[64][32] | B[128][32])
  const int t = threadIdx.x, l = t & 63;
  const int w = t >> 6, wr = (w >> 1) * 32, wc = (w & 1) * 64;
  const int lc = l & 15, lch = l >> 4;
  const int NT = K >> 5;

  const int orig = blockIdx.x;
  const int cpx = gridDim.x >> 3;
  const int sid = (orig & 7) * cpx + (orig >> 3);
  const int bm = (sid / TN) * 64, bn = (sid % TN) * 128;

  const int srow = t >> 2, sc = t & 3;
  const int soff = (sc ^ ((srow >> 1) & 3)) * 8;
  const u16* stA = A + (size_t)(bm + srow) * K + soff;
  const u16* stB = W + (size_t)(bn + srow) * K + soff;
  const size_t rstep = (size_t)64 * K;

#define STAGE(tile)                                       \
  {                                                       \
    u16* d = sm + ((tile) & 3) * 6144 + t * 8;            \
    const int kt = (tile) * 32;                           \
    gl_lds16(stA + kt, d);                                \
    gl_lds16(stB + kt, d + 2048);                         \
    gl_lds16(stB + rstep + kt, d + 4096);                 \
  }

  f32x4 acc[2][4] = {};
  STAGE(0) STAGE(1) STAGE(2)

  const int key = (lch ^ ((lc >> 1) & 3)) * 8;
  for (int tt = 0; tt < NT; ++tt) {
    const int rem = NT - 1 - tt;
    if (rem >= 3) {
      STAGE(tt + 3)
      asm volatile("s_waitcnt vmcnt(9)" ::: "memory");
    } else if (rem == 2) {
      asm volatile("s_waitcnt vmcnt(6)" ::: "memory");
    } else if (rem == 1) {
      asm volatile("s_waitcnt vmcnt(3)" ::: "memory");
    } else {
      asm volatile("s_waitcnt vmcnt(0)" ::: "memory");
    }
    barrier_();
    const u16* bufp = sm + (tt & 3) * 6144;
    bf16x8 af[2], bfv[4];
    #pragma unroll
    for (int mi = 0; mi < 2; mi++)
      af[mi] = *(const bf16x8*)&bufp[(wr + mi * 16 + lc) * 32 + key];
    #pragma unroll
    for (int ni = 0; ni < 4; ni++)
      bfv[ni] = *(const bf16x8*)&bufp[2048 + (wc + ni * 16 + lc) * 32 + key];
    #pragma unroll
    for (int mi = 0; mi < 2; mi++)
      #pragma unroll
      for (int ni = 0; ni < 4; ni++)
        acc[mi][ni] = MFMA16(af[mi], bfv[ni], acc[mi][ni]);
    asm volatile("s_waitcnt lgkmcnt(0)" ::: "memory");
    barrier_();
  }
#undef STAGE

  u16* osm = sm;
  #pragma unroll
  for (int ni = 0; ni < 4; ni++) {
    const int col = wc + ni * 16 + lc;
    const float bb = bias[bn + col];
    const int ckey = col >> 3, clow = col & 7;
    #pragma unroll
    for (int mi = 0; mi < 2; mi++) {
      #pragma unroll
      for (int r = 0; r < 4; r++) {
        const int row = wr + mi * 16 + lch * 4 + r;
        float v = acc[mi][ni][r] + bb;
        if (ACT == 1) v = 0.5f * v * (1.0f + erff(v * 0.70710678118f));
        osm[row * 128 + ((ckey ^ ((row & 7) << 1)) << 3) + clow] = f2bf(v);
      }
    }
  }
  __syncthreads();
  #pragma unroll
  for (int p = 0; p < 4; p++) {
    const int flat = p * 256 + t;
    const int row = flat >> 4, c = flat & 15;
    u16x8 y = *(const u16x8*)&osm[row * 128 + ((c ^ ((row & 7) << 1)) << 3)];
    *(u16x8*)&Ob[(size_t)(bm + row) * N + bn + c * 8] = y;
  }
}

// ---------------------------------------------------------------------------
// transkv: per (bh, jchunk) transpose K and V -> ktg/vtg[bh][d][S] (d-major)
// and compute W[bh][c][d] = sum_jloc gamma^(63-jloc) * V[c*64+jloc][d].
// ---------------------------------------------------------------------------
__global__ __launch_bounds__(256) void transkv(
    const u16* __restrict__ qkvg, u16* __restrict__ ktg, u16* __restrict__ vtg,
    float* __restrict__ Wtab) {
  __shared__ u16 Lk[64 * 72], Lv[64 * 72];
  const int t = threadIdx.x;
  const int bh = blockIdx.x, c = blockIdx.y, b = bh >> 3, h = bh & 7;
  const int jt = c * 64;
  const u16* kptr = qkvg + (size_t)(b * 2048 + jt) * 2048 + 512 + h * 64;
  const u16* vptr = kptr + 512;
  const int r0 = t >> 3, c0 = (t & 7) * 8;
  u16x8 k0 = *(const u16x8*)(kptr + (size_t)r0 * 2048 + c0);
  u16x8 k1 = *(const u16x8*)(kptr + (size_t)(r0 + 32) * 2048 + c0);
  u16x8 v0 = *(const u16x8*)(vptr + (size_t)r0 * 2048 + c0);
  u16x8 v1 = *(const u16x8*)(vptr + (size_t)(r0 + 32) * 2048 + c0);
  #pragma unroll
  for (int e = 0; e < 8; e++) {
    Lk[(c0 + e) * 72 + r0] = k0[e];  Lk[(c0 + e) * 72 + 32 + r0] = k1[e];
    Lv[(c0 + e) * 72 + r0] = v0[e];  Lv[(c0 + e) * 72 + 32 + r0] = v1[e];
  }
  __syncthreads();
  {
    u16* kd = ktg + (size_t)bh * 64 * 2048 + jt;
    u16* vd = vtg + (size_t)bh * 64 * 2048 + jt;
    *(u16x8*)(kd + (size_t)r0 * 2048 + c0)        = *(const u16x8*)&Lk[r0 * 72 + c0];
    *(u16x8*)(kd + (size_t)(r0 + 32) * 2048 + c0) = *(const u16x8*)&Lk[(r0 + 32) * 72 + c0];
    *(u16x8*)(vd + (size_t)r0 * 2048 + c0)        = *(const u16x8*)&Lv[r0 * 72 + c0];
    *(u16x8*)(vd + (size_t)(r0 + 32) * 2048 + c0) = *(const u16x8*)&Lv[(r0 + 32) * 72 + c0];
  }
  if (t < 64) {
    const float gamma = 1.0f - exp2f(-5.0f - (float)h);
    float acc = 0.0f, p = 1.0f;
    for (int jj = 0; jj < 64; jj++) {   // jloc descending 63..0, weight gamma^(63-jloc)
      acc += p * bf2f(Lv[t * 72 + (63 - jj)]);
      p *= gamma;
    }
    Wtab[((size_t)bh * 32 + c) * 64 + t] = acc;
  }
}

// ---------------------------------------------------------------------------
// scan: per bh: Ksum[d] = sum_j K[j][d]; in-place W -> C (carry) scan:
// C_c = gamma^64 * C_{c-1} + W_c.
// ---------------------------------------------------------------------------
__global__ __launch_bounds__(256) void scan_kernel(
    const u16* __restrict__ ktg, float* __restrict__ Ctab, float* __restrict__ ksum) {
  __shared__ float ps[4][64];
  const int t = threadIdx.x, bh = blockIdx.x, h = bh & 7;
  const int a = t & 63, q = t >> 6;
  const u16* kr = ktg + (size_t)bh * 64 * 2048 + (size_t)a * 2048 + q * 512;
  float s = 0.0f;
  for (int j = 0; j < 512; j += 8) {
    u16x8 v = *(const u16x8*)(kr + j);
    #pragma unroll
    for (int e = 0; e < 8; e++) s += bf2f(v[e]);
  }
  ps[q][a] = s;
  __syncthreads();
  if (t < 64) {
    ksum[bh * 64 + t] = ps[0][t] + ps[1][t] + ps[2][t] + ps[3][t];
    const float gamma = 1.0f - exp2f(-5.0f - (float)h);
    const float g64 = exp2f(64.0f * log2f(gamma));
    float* Wp = Ctab + (size_t)bh * 32 * 64 + t;
    float C = 0.0f;
    for (int c = 0; c < 32; c++) {
      C = C * g64 + Wp[c * 64];
      Wp[c * 64] = C;
    }
  }
}

// ---------------------------------------------------------------------------
// vtk: per bh: VtK[b][a] = sum_j V[j][b]*K[j][a]  (= vtg @ ktg^T), 64x64 bf16.
// ---------------------------------------------------------------------------
__global__ __launch_bounds__(256) void vtk_kernel(
    const u16* __restrict__ vtg, const u16* __restrict__ ktg, u16* __restrict__ vtk) {
  __shared__ float red[3][4096];
  const int t = threadIdx.x, l = t & 63, w = t >> 6;
  const int bh = blockIdx.x;
  const int lc = l & 15, lch = l >> 4;
  const u16* vb = vtg + (size_t)bh * 64 * 2048;
  const u16* kb = ktg + (size_t)bh * 64 * 2048;
  f32x4 acc[4][4] = {};
  for (int it = 0; it < 16; ++it) {
    const int j0 = w * 512 + it * 32 + lch * 8;
    bf16x8 af[4], bfr[4];
    #pragma unroll
    for (int mt = 0; mt < 4; mt++)
      af[mt] = *(const bf16x8*)(vb + (size_t)(mt * 16 + lc) * 2048 + j0);
    #pragma unroll
    for (int nt = 0; nt < 4; nt++)
      bfr[nt] = *(const bf16x8*)(kb + (size_t)(nt * 16 + lc) * 2048 + j0);
    #pragma unroll
    for (int mt = 0; mt < 4; mt++)
      #pragma unroll
      for (int nt = 0; nt < 4; nt++)
        acc[mt][nt] = MFMA16(af[mt], bfr[nt], acc[mt][nt]);
  }
  if (w > 0) {
    #pragma unroll
    for (int mt = 0; mt < 4; mt++)
      #pragma unroll
      for (int nt = 0; nt < 4; nt++)
        #pragma unroll
        for (int r = 0; r < 4; r++)
          red[w - 1][(mt * 16 + lch * 4 + r) * 64 + nt * 16 + lc] = acc[mt][nt][r];
  }
  __syncthreads();
  if (w == 0) {
    u16* out = vtk + (size_t)bh * 64 * 64;
    #pragma unroll
    for (int mt = 0; mt < 4; mt++)
      #pragma unroll
      for (int nt = 0; nt < 4; nt++)
        #pragma unroll
        for (int r = 0; r < 4; r++) {
          int row = mt * 16 + lch * 4 + r, col = nt * 16 + lc;
          float v = acc[mt][nt][r] + red[0][row * 64 + col] + red[1][row * 64 + col] +
                    red[2][row * 64 + col];
          out[row * 64 + col] = f2bf(v);
        }
  }
}

// ---------------------------------------------------------------------------
// ret_out: o^T[b][i] = rrs_i*(L@V_chunk + gamma^(iloc+1)*C_{c-1}) + Q@VtK^T,
// den_i = q_i.Ksum + sqrt(rowsum_i); then /den, per-head LN, silu(g) gate.
// ---------------------------------------------------------------------------
__global__ __launch_bounds__(512) void ret_out(
    const u16* __restrict__ qkvg, const u16* __restrict__ vtg,
    const u16* __restrict__ vtk, const float* __restrict__ Ctab,
    const float* __restrict__ ksum, u16* __restrict__ gated) {
  const int S = 2048, DD = 2048;
  const int bh = blockIdx.x, b = bh >> 3, h = bh & 7;
  const int t = threadIdx.x, l = t & 63, w = t >> 6;
  const int lid = l & 31, hi = l >> 5;
  const int wrow = blockIdx.y * 256 + w * 32;
  const int i_q = wrow + lid;
  const int chunk = wrow >> 6;          // wave-uniform
  const int iloc = i_q & 63;

  __shared__ __align__(16) u16 sm[18432];
  float* smf = (float*)sm;

  const size_t base = (size_t)b * S * DD + (size_t)h * 64;
  const u16* qp = qkvg + base;
  const u16* gp = qkvg + base + 1536;

  const float gamma = 1.0f - exp2f(-5.0f - (float)h);
  const float l2g = log2f(gamma);
  const float rowsum = (1.0f - exp2f((float)(i_q + 1) * l2g)) * exp2f(5.0f + (float)h);
  const float rrs = rsqrtf(rowsum);

  // generate L (lower-tri gamma^(iloc-jloc), bf16) into LDS
  {
    const int il = t >> 3, j0 = (t & 7) * 8;
    u16x8 row;
    #pragma unroll
    for (int e = 0; e < 8; e++) {
      int d = il - (j0 + e);
      row[e] = (d >= 0) ? f2bf(exp2f((float)d * l2g)) : (u16)0;
    }
    *(u16x8*)&sm[il * 72 + j0] = row;
  }
  // stage carries (chunks by*4-1 .. by*4+2) and Ksum
  if (t < 256) {
    int cc = blockIdx.y * 4 - 1 + (t >> 6);
    smf[4608 + t] = (cc >= 0) ? Ctab[((size_t)bh * 32 + cc) * 64 + (t & 63)] : 0.0f;
  } else if (t < 320) {
    smf[4864 + (t - 256)] = ksum[bh * 64 + (t - 256)];
  }
  __syncthreads();

  bf16x8 qf[4];
  #pragma unroll
  for (int kc = 0; kc < 4; kc++)
    qf[kc] = *(const bf16x8*)(qp + (size_t)i_q * DD + kc * 16 + 8 * hi);

  const u16* vt_b = vtg + (size_t)bh * 64 * S;
  const u16* vk_b = vtk + (size_t)bh * 64 * 64;

  f32x16 accO0, accO1;
  #pragma unroll
  for (int r = 0; r < 16; r++) { accO0[r] = 0.0f; accO1[r] = 0.0f; }

  // 1) L @ V_chunk
  #pragma unroll
  for (int kc = 0; kc < 4; kc++) {
    bf16x8 lb = *(const bf16x8*)&sm[iloc * 72 + kc * 16 + hi * 8];
    bf16x8 va0 = *(const bf16x8*)(vt_b + (size_t)lid * S + chunk * 64 + kc * 16 + hi * 8);
    bf16x8 va1 = *(const bf16x8*)(vt_b + (size_t)(lid + 32) * S + chunk * 64 + kc * 16 + hi * 8);
    accO0 = MFMA32(va0, lb, accO0);
    accO1 = MFMA32(va1, lb, accO1);
  }
  // 2) carry
  {
    const float gpw = exp2f((float)(iloc + 1) * l2g);
    const float* Cst = &smf[4608 + (w >> 1) * 64];
    #pragma unroll
    for (int r = 0; r < 16; r++) {
      int br = (r & 3) + 8 * (r >> 2) + 4 * hi;
      accO0[r] += gpw * Cst[br];
      accO1[r] += gpw * Cst[32 + br];
    }
  }
  // 3) scale decay part by rrs
  #pragma unroll
  for (int r = 0; r < 16; r++) { accO0[r] *= rrs; accO1[r] *= rrs; }
  // 4) Q @ VtK^T
  #pragma unroll
  for (int kc = 0; kc < 4; kc++) {
    bf16x8 ka0 = *(const bf16x8*)(vk_b + (size_t)lid * 64 + kc * 16 + hi * 8);
    bf16x8 ka1 = *(const bf16x8*)(vk_b + (size_t)(lid + 32) * 64 + kc * 16 + hi * 8);
    accO0 = MFMA32(ka0, qf[kc], accO0);
    accO1 = MFMA32(ka1, qf[kc], accO1);
  }
  // 5) den
  float dsum = 0.0f;
  #pragma unroll
  for (int kc = 0; kc < 4; kc++) {
    const float* Ks = &smf[4864 + kc * 16 + hi * 8];
    #pragma unroll
    for (int e = 0; e < 8; e++) dsum += bfel(qf[kc], e) * Ks[e];
  }
  dsum += __shfl_xor(dsum, 32);
  float den = dsum + sqrtf(rowsum);
  float rden = 1.0f / fmaxf(fabsf(den), 1.0f);

  // 6) normalize + per-head LN
  float o0[16], o1[16];
  float s1 = 0.0f, s2 = 0.0f;
  #pragma unroll
  for (int r = 0; r < 16; r++) {
    o0[r] = accO0[r] * rden; s1 += o0[r]; s2 += o0[r] * o0[r];
    o1[r] = accO1[r] * rden; s1 += o1[r]; s2 += o1[r] * o1[r];
  }
  s1 += __shfl_xor(s1, 32);
  s2 += __shfl_xor(s2, 32);
  float mu = s1 * (1.0f / 64.0f);
  float var = s2 * (1.0f / 64.0f) - mu * mu;
  float rv = rsqrtf(var + 1e-6f);

  __syncthreads();   // all waves done with L/Ct/Ksum regions

  u16* Ot = sm + w * 2304;
  #pragma unroll
  for (int r = 0; r < 16; r++) {
    int d = (r & 3) + 8 * (r >> 2) + 4 * hi;
    Ot[lid * 72 + d]      = f2bf((o0[r] - mu) * rv);
    Ot[lid * 72 + 32 + d] = f2bf((o1[r] - mu) * rv);
  }
  {
    const int i2 = l >> 1, half = l & 1;
    const int row = wrow + i2;
    #pragma unroll
    for (int c = 0; c < 4; c++) {
      u16x8 y8 = *(const u16x8*)&Ot[i2 * 72 + half * 32 + c * 8];
      u16x8 g8 = *(const u16x8*)(gp + (size_t)row * DD + half * 32 + c * 8);
      u16x8 o8;
      #pragma unroll
      for (int e = 0; e < 8; e++) {
        float gv = bf2f(g8[e]);
        float sg = gv / (1.0f + __expf(-gv));
        o8[e] = f2bf(bf2f(y8[e]) * sg);
      }
      *(u16x8*)&gated[((size_t)(b * S + row)) * 512 + h * 64 + half * 32 + c * 8] = o8;
    }
  }
}

// ---------------------------------------------------------------------------
// add_lnT: y = LN(A + B) over D=512; A fp32 (AF32=1) or bf16 (AF32=0),
// B bf16. Writes fp32 (WF=1) and/or bf16 (Ob != null). One wave per row.
// ---------------------------------------------------------------------------
template <int AF32, int WF>
__global__ __launch_bounds__(256) void add_lnT(
    const void* __restrict__ Ap, const u16* __restrict__ Bv,
    const float* __restrict__ gam, const float* __restrict__ bet, float eps,
    float* __restrict__ Of, u16* __restrict__ Ob) {
  int row = blockIdx.x * 4 + (threadIdx.x >> 6);
  int l = threadIdx.x & 63;
  float x[8];
  u16x8 cv = *(const u16x8*)(Bv + (size_t)row * 512 + l * 8);
  if (AF32) {
    const float* a = (const float*)Ap + (size_t)row * 512 + l * 8;
    f32x4 a0 = *(const f32x4*)a, a1 = *(const f32x4*)(a + 4);
    #pragma unroll
    for (int e = 0; e < 4; e++) { x[e] = a0[e] + bf2f(cv[e]); x[4 + e] = a1[e] + bf2f(cv[4 + e]); }
  } else {
    u16x8 av = *(const u16x8*)((const u16*)Ap + (size_t)row * 512 + l * 8);
    #pragma unroll
    for (int e = 0; e < 8; e++) x[e] = bf2f(av[e]) + bf2f(cv[e]);
  }
  float s = 0.f, s2 = 0.f;
  #pragma unroll
  for (int e = 0; e < 8; e++) { s += x[e]; s2 += x[e] * x[e]; }
  #pragma unroll
  for (int m = 1; m <= 32; m <<= 1) { s += __shfl_xor(s, m); s2 += __shfl_xor(s2, m); }
  float mu = s * (1.0f / 512.0f);
  float var = s2 * (1.0f / 512.0f) - mu * mu;
  float rinv = rsqrtf(var + eps);
  f32x4 g0 = *(const f32x4*)(gam + l * 8), g1 = *(const f32x4*)(gam + l * 8 + 4);
  f32x4 b0 = *(const f32x4*)(bet + l * 8), b1 = *(const f32x4*)(bet + l * 8 + 4);
  f32x4 y0, y1;
  #pragma unroll
  for (int e = 0; e < 4; e++) {
    y0[e] = (x[e] - mu) * rinv * g0[e] + b0[e];
    y1[e] = (x[4 + e] - mu) * rinv * g1[e] + b1[e];
  }
  if (WF) {
    float* op = Of + (size_t)row * 512 + l * 8;
    *(f32x4*)op = y0;
    *(f32x4*)(op + 4) = y1;
  }
  if (Ob) {
    u16x8 rb_;
    #pragma unroll
    for (int e = 0; e < 4; e++) { rb_[e] = f2bf(y0[e]); rb_[4 + e] = f2bf(y1[e]); }
    *(u16x8*)(Ob + (size_t)row * 512 + l * 8) = rb_;
  }
}

// ---------------------------------------------------------------------------
// In-place sub-LN over FFN=2048 (bf16), eps 1e-6, affine. One wave per row.
// ---------------------------------------------------------------------------
__global__ __launch_bounds__(256) void subln_ffn(
    u16* __restrict__ hbuf, const float* __restrict__ gam, const float* __restrict__ bet) {
  int row = blockIdx.x * 4 + (threadIdx.x >> 6);
  int l = threadIdx.x & 63;
  u16* p = hbuf + (size_t)row * 2048;
  float x[32];
  #pragma unroll
  for (int cch = 0; cch < 4; cch++) {
    u16x8 v = *(const u16x8*)(p + cch * 512 + l * 8);
    #pragma unroll
    for (int e = 0; e < 8; e++) x[cch * 8 + e] = bf2f(v[e]);
  }
  float s = 0.f, s2 = 0.f;
  #pragma unroll
  for (int e = 0; e < 32; e++) { s += x[e]; s2 += x[e] * x[e]; }
  #pragma unroll
  for (int m = 1; m <= 32; m <<= 1) { s += __shfl_xor(s, m); s2 += __shfl_xor(s2, m); }
  float mu = s * (1.0f / 2048.0f);
  float var = s2 * (1.0f / 2048.0f) - mu * mu;
  float rinv = rsqrtf(var + 1e-6f);
  #pragma unroll
  for (int cch = 0; cch < 4; cch++) {
    int col = cch * 512 + l * 8;
    f32x4 g0 = *(const f32x4*)(gam + col), g1 = *(const f32x4*)(gam + col + 4);
    f32x4 b0 = *(const f32x4*)(bet + col), b1 = *(const f32x4*)(bet + col + 4);
    u16x8 o;
    #pragma unroll
    for (int e = 0; e < 4; e++) {
      o[e]     = f2bf((x[cch * 8 + e]     - mu) * rinv * g0[e] + b0[e]);
      o[4 + e] = f2bf((x[cch * 8 + 4 + e] - mu) * rinv * g1[e] + b1[e]);
    }
    *(u16x8*)(p + col) = o;
  }
}

// ---------------------------------------------------------------------------
extern "C" void kernel_launch(void* const* d_in, const int* in_sizes, int n_in,
                              void* d_out, int out_size, void* d_ws, size_t ws_size,
                              hipStream_t stream) {
  const float* src  = (const float*)d_in[0];
  const float* wq   = (const float*)d_in[3];
  const float* bq   = (const float*)d_in[4];
  const float* wk   = (const float*)d_in[5];
  const float* bk   = (const float*)d_in[6];
  const float* wv   = (const float*)d_in[7];
  const float* bv   = (const float*)d_in[8];
  const float* wg   = (const float*)d_in[9];
  const float* bg   = (const float*)d_in[10];
  const float* wo   = (const float*)d_in[11];
  const float* bo   = (const float*)d_in[12];
  const float* fc1w = (const float*)d_in[13];
  const float* fc1b = (const float*)d_in[14];
  const float* fc2w = (const float*)d_in[15];
  const float* fc2b = (const float*)d_in[16];
  const float* lng  = (const float*)d_in[17];
  const float* lnb  = (const float*)d_in[18];
  const float* n0g  = (const float*)d_in[19];
  const float* n0b  = (const float*)d_in[20];
  const float* n1g  = (const float*)d_in[21];
  const float* n1b  = (const float*)d_in[22];

  if (ws_size < 91242496u) return;  // need ~91.3 MB scratch

  char* ws = (char*)d_ws;
  u16*   src_bf = (u16*)(ws + 0);
  u16*   Wcat   = (u16*)(ws + 8388608);
  u16*   wo_bf  = (u16*)(ws + 10485760);
  u16*   fc1_bf = (u16*)(ws + 11010048);
  u16*   fc2_bf = (u16*)(ws + 13107200);
  float* bcat   = (float*)(ws + 15204352);
  u16*   qkvg   = (u16*)(ws + 15212544);   // 32 MB; reused as h1 after retention
  u16*   gated  = (u16*)(ws + 48766976);   // 8 MB
  u16*   attn   = (u16*)(ws + 57155584);   // 8 MB; reused as y (fc2 out)
  u16*   vtg    = (u16*)(ws + 65544192);   // 8 MB
  u16*   ktg    = (u16*)(ws + 73932800);   // 8 MB
  u16*   xbf    = (u16*)(ws + 82321408);   // 8 MB
  float* Ctab   = (float*)(ws + 90710016); // 256 KB (W then carries, in place)
  u16*   vtkb   = (u16*)(ws + 90972160);   // 256 KB
  float* ksumb  = (float*)(ws + 91234304); // 8 KB

  // 1. casts / weight concat
  prep_cast<<<3713, 256, 0, stream>>>(src, wq, wk, wv, wg, wo, fc1w, fc2w,
                                      bq, bk, bv, bg,
                                      src_bf, Wcat, wo_bf, fc1_bf, fc2_bf, bcat);
  // 2. QKVG projection: (8192x512) @ (2048x512)^T  [256^2, BK=128, NT=4]
  gemm_fat<0><<<256, 512, 0, stream>>>(src_bf, Wcat, bcat, qkvg, 2048, 512, 8);
  // 3. transpose K,V (+ per-chunk decay sums W)
  transkv<<<dim3(32, 32), 256, 0, stream>>>(qkvg, ktg, vtg, Ctab);
  // 4. Ksum + carry scan (in place on Ctab)
  scan_kernel<<<32, 256, 0, stream>>>(ktg, Ctab, ksumb);
  // 5. VtK = V^T K (64x64 per head)
  vtk_kernel<<<32, 256, 0, stream>>>(vtg, ktg, vtkb);
  // 6. retention output + per-head LN + silu gating
  ret_out<<<dim3(32, 8), 512, 0, stream>>>(qkvg, vtg, vtkb, Ctab, ksumb, gated);
  // 7. output projection (8192x512 @ 512x512^T)
  gemm_m64_ring<0><<<512, 256, 0, stream>>>(gated, wo_bf, bo, attn, 512, 512, 4);
  // 8. x = LN(src + attn), n0, eps 1e-5 -> bf16 only
  add_lnT<1, 0><<<2048, 256, 0, stream>>>(src, attn, n0g, n0b, 1e-5f, nullptr, xbf);
  // 9. fc1 + exact gelu -> h1 (aliases qkvg)  [256^2, BK=128, NT=4]
  gemm_fat<1><<<256, 512, 0, stream>>>(xbf, fc1_bf, fc1b, qkvg, 2048, 512, 8);
  // 10. sub-LN over 2048 (in place)
  subln_ffn<<<2048, 256, 0, stream>>>(qkvg, lng, lnb);
  // 11. fc2 -> y (aliases attn)
  gemm_m64_ring<0><<<512, 256, 0, stream>>>(qkvg, fc2_bf, fc2b, attn, 512, 2048, 4);
  // 12. out = LN(x + y), n1, eps 1e-5 -> d_out (fp32)
  add_lnT<0, 1><<<2048, 256, 0, stream>>>(xbf, attn, n1g, n1b, 1e-5f, (float*)d_out, nullptr);
}

// Round 14
// 178.679 us; speedup vs baseline: 1.0832x; 1.0832x over previous
//
#include <hip/hip_runtime.h>
#include <hip/hip_bf16.h>
#include <math.h>

#define DEV __device__ __forceinline__

typedef __attribute__((ext_vector_type(4))) float f32x4;
typedef __attribute__((ext_vector_type(16))) float f32x16;
typedef __attribute__((ext_vector_type(8))) short bf16x8;     // 8 bf16 in 4 VGPRs (MFMA frag)
typedef __attribute__((ext_vector_type(8))) unsigned short u16x8;
typedef unsigned short u16;
typedef unsigned int u32;

DEV u16 f2bf(float f) {
  union { float f; u32 u; } v; v.f = f;
  u32 r = v.u + 0x7fffu + ((v.u >> 16) & 1u);
  return (u16)(r >> 16);
}
DEV float bf2f(u16 h) {
  union { u32 u; float f; } v; v.u = ((u32)h) << 16;
  return v.f;
}
DEV float bfel(bf16x8 v, int e) {
  union { bf16x8 b; u16x8 u; } x; x.b = v; return bf2f(x.u[e]);
}

DEV void gl_lds16(const u16* g, u16* s) {
  __builtin_amdgcn_global_load_lds((const __attribute__((address_space(1))) void*)g,
                                   (__attribute__((address_space(3))) void*)s, 16, 0, 0);
}

// raw barrier (no implicit vmcnt drain), pinned against compiler motion
DEV void barrier_() {
  __builtin_amdgcn_sched_barrier(0);
  asm volatile("" ::: "memory");
  __builtin_amdgcn_s_barrier();
  asm volatile("" ::: "memory");
  __builtin_amdgcn_sched_barrier(0);
}

#define MFMA16(a, b, c) __builtin_amdgcn_mfma_f32_16x16x32_bf16((a), (b), (c), 0, 0, 0)
#define MFMA32(a, b, c) __builtin_amdgcn_mfma_f32_32x32x16_bf16((a), (b), (c), 0, 0, 0)

// ---------------------------------------------------------------------------
// Prep: cast src + weights to bf16; concat wq|wk|wv|wg -> Wcat (k scaled 0.125);
// concat biases bq|bk*0.125|bv|bg -> bcat.
// ---------------------------------------------------------------------------
DEV void cast8(const float* in, u16* out, float s) {
  f32x4 a = *(const f32x4*)in;
  f32x4 b = *(const f32x4*)(in + 4);
  u16x8 r;
  r[0] = f2bf(a[0] * s); r[1] = f2bf(a[1] * s); r[2] = f2bf(a[2] * s); r[3] = f2bf(a[3] * s);
  r[4] = f2bf(b[0] * s); r[5] = f2bf(b[1] * s); r[6] = f2bf(b[2] * s); r[7] = f2bf(b[3] * s);
  *(u16x8*)out = r;
}

__global__ __launch_bounds__(256) void prep_cast(
    const float* __restrict__ src, const float* __restrict__ wq, const float* __restrict__ wk,
    const float* __restrict__ wv, const float* __restrict__ wg, const float* __restrict__ wo,
    const float* __restrict__ fc1, const float* __restrict__ fc2,
    const float* __restrict__ bq, const float* __restrict__ bk,
    const float* __restrict__ bv, const float* __restrict__ bg,
    u16* __restrict__ src_bf, u16* __restrict__ Wcat, u16* __restrict__ wo_bf,
    u16* __restrict__ fc1_bf, u16* __restrict__ fc2_bf, float* __restrict__ bcat) {
  int u = blockIdx.x * 256 + threadIdx.x;
  if (u < 524288) {
    cast8(src + (size_t)u * 8, src_bf + (size_t)u * 8, 1.0f);
  } else if (u < 557056) {
    int v = u - 524288; cast8(wq + (size_t)v * 8, Wcat + (size_t)v * 8, 1.0f);
  } else if (u < 589824) {
    int v = u - 557056; cast8(wk + (size_t)v * 8, Wcat + 262144 + (size_t)v * 8, 0.125f);
  } else if (u < 622592) {
    int v = u - 589824; cast8(wv + (size_t)v * 8, Wcat + 524288 + (size_t)v * 8, 1.0f);
  } else if (u < 655360) {
    int v = u - 622592; cast8(wg + (size_t)v * 8, Wcat + 786432 + (size_t)v * 8, 1.0f);
  } else if (u < 688128) {
    int v = u - 655360; cast8(wo + (size_t)v * 8, wo_bf + (size_t)v * 8, 1.0f);
  } else if (u < 819200) {
    int v = u - 688128; cast8(fc1 + (size_t)v * 8, fc1_bf + (size_t)v * 8, 1.0f);
  } else if (u < 950272) {
    int v = u - 819200; cast8(fc2 + (size_t)v * 8, fc2_bf + (size_t)v * 8, 1.0f);
  } else if (u < 950528) {
    int v = u - 950272;
    #pragma unroll
    for (int e = 0; e < 8; e++) {
      int c = v * 8 + e;
      float val;
      if (c < 512)       val = bq[c];
      else if (c < 1024) val = bk[c - 512] * 0.125f;
      else if (c < 1536) val = bv[c - 1024];
      else               val = bg[c - 1536];
      bcat[c] = val;
    }
  }
}

// ---------------------------------------------------------------------------
// gemm_v3 (R8 config, best measured): 128x128 tile, BK=64, 4 waves, dbuf 64KB,
// counted-vmcnt pipeline (vmcnt(8)), raw barriers, chunk-XOR swizzle both
// sides, LDS-bounce epilogue.
// ---------------------------------------------------------------------------
template <int ACT>
__global__ __launch_bounds__(256) void gemm_v3(
    const u16* __restrict__ A, const u16* __restrict__ W, const float* __restrict__ bias,
    u16* __restrict__ Ob, int N, int K, int TN) {
  __shared__ __align__(16) u16 sm[2][16384];   // [buf][A:0..8191 | B:8192..16383]
  const int t = threadIdx.x, l = t & 63;
  const int w = t >> 6, wr = (w >> 1) * 64, wc = (w & 1) * 64;
  const int lc = l & 15, lch = l >> 4;
  const int NT = K >> 6;

  const int orig = blockIdx.x;
  const int cpx = gridDim.x >> 3;
  const int sid = (orig & 7) * cpx + (orig >> 3);
  const int bm = (sid / TN) * 128, bn = (sid % TN) * 128;

  const int srow = t >> 3, sc8 = t & 7;
  const u16* stA = A + (size_t)(bm + srow) * K + ((sc8 ^ (srow & 7)) * 8);
  const u16* stB = W + (size_t)(bn + srow) * K + ((sc8 ^ (srow & 7)) * 8);

#define STAGE(bidx, kt)                                                        \
  {                                                                            \
    u16* d = (u16*)sm[bidx] + t * 8;                                           \
    _Pragma("unroll")                                                          \
    for (int j = 0; j < 4; j++)                                                \
      gl_lds16(stA + (size_t)j * 32 * K + (kt), d + j * 2048);                 \
    _Pragma("unroll")                                                          \
    for (int j = 0; j < 4; j++)                                                \
      gl_lds16(stB + (size_t)j * 32 * K + (kt), d + 8192 + j * 2048);          \
  }

  f32x4 acc[4][4] = {};

  STAGE(0, 0)

  for (int tt = 0; tt < NT; ++tt) {
    if (tt + 1 < NT) {
      STAGE((tt + 1) & 1, (tt + 1) * 64)
      asm volatile("s_waitcnt vmcnt(8)" ::: "memory");   // STAGE(tt) landed
    } else {
      asm volatile("s_waitcnt vmcnt(0)" ::: "memory");
    }
    barrier_();
    const u16* bufp = sm[tt & 1];
    bf16x8 af[4][2], bfv[4][2];
    #pragma unroll
    for (int mi = 0; mi < 4; mi++) {
      const int row = wr + mi * 16 + lc;
      #pragma unroll
      for (int ks = 0; ks < 2; ks++) {
        const int ch = ks * 4 + lch;
        af[mi][ks] = *(const bf16x8*)&bufp[row * 64 + ((ch ^ (row & 7)) * 8)];
      }
    }
    #pragma unroll
    for (int ni = 0; ni < 4; ni++) {
      const int row = wc + ni * 16 + lc;
      #pragma unroll
      for (int ks = 0; ks < 2; ks++) {
        const int ch = ks * 4 + lch;
        bfv[ni][ks] = *(const bf16x8*)&bufp[8192 + row * 64 + ((ch ^ (row & 7)) * 8)];
      }
    }
    #pragma unroll
    for (int ks = 0; ks < 2; ks++)
      #pragma unroll
      for (int mi = 0; mi < 4; mi++)
        #pragma unroll
        for (int ni = 0; ni < 4; ni++)
          acc[mi][ni] = MFMA16(af[mi][ks], bfv[ni][ks], acc[mi][ni]);
    asm volatile("s_waitcnt lgkmcnt(0)" ::: "memory");   // reads done before overwrite
    barrier_();
  }
#undef STAGE

  u16* osm = (u16*)sm;
  #pragma unroll
  for (int ni = 0; ni < 4; ni++) {
    const int col = wc + ni * 16 + lc;
    const float bb = bias[bn + col];
    const int ckey = col >> 3, clow = col & 7;
    #pragma unroll
    for (int mi = 0; mi < 4; mi++) {
      #pragma unroll
      for (int r = 0; r < 4; r++) {
        const int row = wr + mi * 16 + lch * 4 + r;
        float v = acc[mi][ni][r] + bb;
        if (ACT == 1) v = 0.5f * v * (1.0f + erff(v * 0.70710678118f));
        osm[row * 128 + ((ckey ^ ((row & 7) << 1)) << 3) + clow] = f2bf(v);
      }
    }
  }
  __syncthreads();
  #pragma unroll
  for (int p = 0; p < 8; p++) {
    const int flat = p * 256 + t;
    const int row = flat >> 4, c = flat & 15;
    u16x8 y = *(const u16x8*)&osm[row * 128 + ((c ^ ((row & 7) << 1)) << 3)];
    *(u16x8*)&Ob[(size_t)(bm + row) * N + bn + c * 8] = y;
  }
}

// ---------------------------------------------------------------------------
// gemm_m64 (R8 config): 64x128 tile, BK=64, dbuf 48KB, counted vmcnt(6).
// For N=512 GEMMs (wo, fc2).
// ---------------------------------------------------------------------------
template <int ACT>
__global__ __launch_bounds__(256) void gemm_m64(
    const u16* __restrict__ A, const u16* __restrict__ W, const float* __restrict__ bias,
    u16* __restrict__ Ob, int N, int K, int TN) {
  __shared__ __align__(16) u16 sm[2][12288];   // [buf][A:0..4095 | B:4096..12287]
  const int t = threadIdx.x, l = t & 63;
  const int w = t >> 6, wr = (w >> 1) * 32, wc = (w & 1) * 64;
  const int lc = l & 15, lch = l >> 4;
  const int NT = K >> 6;

  const int orig = blockIdx.x;
  const int cpx = gridDim.x >> 3;
  const int sid = (orig & 7) * cpx + (orig >> 3);
  const int bm = (sid / TN) * 64, bn = (sid % TN) * 128;

  const int srow = t >> 3, sc8 = t & 7;
  const u16* stA = A + (size_t)(bm + srow) * K + ((sc8 ^ (srow & 7)) * 8);
  const u16* stB = W + (size_t)(bn + srow) * K + ((sc8 ^ (srow & 7)) * 8);

#define STAGE(bidx, kt)                                                        \
  {                                                                            \
    u16* d = (u16*)sm[bidx] + t * 8;                                           \
    _Pragma("unroll")                                                          \
    for (int j = 0; j < 2; j++)                                                \
      gl_lds16(stA + (size_t)j * 32 * K + (kt), d + j * 2048);                 \
    _Pragma("unroll")                                                          \
    for (int j = 0; j < 4; j++)                                                \
      gl_lds16(stB + (size_t)j * 32 * K + (kt), d + 4096 + j * 2048);          \
  }

  f32x4 acc[2][4] = {};

  STAGE(0, 0)

  for (int tt = 0; tt < NT; ++tt) {
    if (tt + 1 < NT) {
      STAGE((tt + 1) & 1, (tt + 1) * 64)
      asm volatile("s_waitcnt vmcnt(6)" ::: "memory");
    } else {
      asm volatile("s_waitcnt vmcnt(0)" ::: "memory");
    }
    barrier_();
    const u16* bufp = sm[tt & 1];
    bf16x8 af[2][2], bfv[4][2];
    #pragma unroll
    for (int mi = 0; mi < 2; mi++) {
      const int row = wr + mi * 16 + lc;
      #pragma unroll
      for (int ks = 0; ks < 2; ks++) {
        const int ch = ks * 4 + lch;
        af[mi][ks] = *(const bf16x8*)&bufp[row * 64 + ((ch ^ (row & 7)) * 8)];
      }
    }
    #pragma unroll
    for (int ni = 0; ni < 4; ni++) {
      const int row = wc + ni * 16 + lc;
      #pragma unroll
      for (int ks = 0; ks < 2; ks++) {
        const int ch = ks * 4 + lch;
        bfv[ni][ks] = *(const bf16x8*)&bufp[4096 + row * 64 + ((ch ^ (row & 7)) * 8)];
      }
    }
    #pragma unroll
    for (int ks = 0; ks < 2; ks++)
      #pragma unroll
      for (int mi = 0; mi < 2; mi++)
        #pragma unroll
        for (int ni = 0; ni < 4; ni++)
          acc[mi][ni] = MFMA16(af[mi][ks], bfv[ni][ks], acc[mi][ni]);
    asm volatile("s_waitcnt lgkmcnt(0)" ::: "memory");
    barrier_();
  }
#undef STAGE

  u16* osm = (u16*)sm;
  #pragma unroll
  for (int ni = 0; ni < 4; ni++) {
    const int col = wc + ni * 16 + lc;
    const float bb = bias[bn + col];
    const int ckey = col >> 3, clow = col & 7;
    #pragma unroll
    for (int mi = 0; mi < 2; mi++) {
      #pragma unroll
      for (int r = 0; r < 4; r++) {
        const int row = wr + mi * 16 + lch * 4 + r;
        float v = acc[mi][ni][r] + bb;
        if (ACT == 1) v = 0.5f * v * (1.0f + erff(v * 0.70710678118f));
        osm[row * 128 + ((ckey ^ ((row & 7) << 1)) << 3) + clow] = f2bf(v);
      }
    }
  }
  __syncthreads();
  #pragma unroll
  for (int p = 0; p < 4; p++) {
    const int flat = p * 256 + t;
    const int row = flat >> 4, c = flat & 15;
    u16x8 y = *(const u16x8*)&osm[row * 128 + ((c ^ ((row & 7) << 1)) << 3)];
    *(u16x8*)&Ob[(size_t)(bm + row) * N + bn + c * 8] = y;
  }
}

// ---------------------------------------------------------------------------
// transkv: per (bh, jchunk) transpose K and V -> ktg/vtg[bh][d][S] (d-major)
// and compute W[bh][c][d] = sum_jloc gamma^(63-jloc) * V[c*64+jloc][d].
// ---------------------------------------------------------------------------
__global__ __launch_bounds__(256) void transkv(
    const u16* __restrict__ qkvg, u16* __restrict__ ktg, u16* __restrict__ vtg,
    float* __restrict__ Wtab) {
  __shared__ u16 Lk[64 * 72], Lv[64 * 72];
  const int t = threadIdx.x;
  const int bh = blockIdx.x, c = blockIdx.y, b = bh >> 3, h = bh & 7;
  const int jt = c * 64;
  const u16* kptr = qkvg + (size_t)(b * 2048 + jt) * 2048 + 512 + h * 64;
  const u16* vptr = kptr + 512;
  const int r0 = t >> 3, c0 = (t & 7) * 8;
  u16x8 k0 = *(const u16x8*)(kptr + (size_t)r0 * 2048 + c0);
  u16x8 k1 = *(const u16x8*)(kptr + (size_t)(r0 + 32) * 2048 + c0);
  u16x8 v0 = *(const u16x8*)(vptr + (size_t)r0 * 2048 + c0);
  u16x8 v1 = *(const u16x8*)(vptr + (size_t)(r0 + 32) * 2048 + c0);
  #pragma unroll
  for (int e = 0; e < 8; e++) {
    Lk[(c0 + e) * 72 + r0] = k0[e];  Lk[(c0 + e) * 72 + 32 + r0] = k1[e];
    Lv[(c0 + e) * 72 + r0] = v0[e];  Lv[(c0 + e) * 72 + 32 + r0] = v1[e];
  }
  __syncthreads();
  {
    u16* kd = ktg + (size_t)bh * 64 * 2048 + jt;
    u16* vd = vtg + (size_t)bh * 64 * 2048 + jt;
    *(u16x8*)(kd + (size_t)r0 * 2048 + c0)        = *(const u16x8*)&Lk[r0 * 72 + c0];
    *(u16x8*)(kd + (size_t)(r0 + 32) * 2048 + c0) = *(const u16x8*)&Lk[(r0 + 32) * 72 + c0];
    *(u16x8*)(vd + (size_t)r0 * 2048 + c0)        = *(const u16x8*)&Lv[r0 * 72 + c0];
    *(u16x8*)(vd + (size_t)(r0 + 32) * 2048 + c0) = *(const u16x8*)&Lv[(r0 + 32) * 72 + c0];
  }
  if (t < 64) {
    const float gamma = 1.0f - exp2f(-5.0f - (float)h);
    float acc = 0.0f, p = 1.0f;
    for (int jj = 0; jj < 64; jj++) {   // jloc descending 63..0, weight gamma^(63-jloc)
      acc += p * bf2f(Lv[t * 72 + (63 - jj)]);
      p *= gamma;
    }
    Wtab[((size_t)bh * 32 + c) * 64 + t] = acc;
  }
}

// ---------------------------------------------------------------------------
// scanvtk: merged scan + vtk (one launch, same grid). Per bh:
//  (1) Ksum[d] = sum_j K[j][d]; in-place W -> C carry scan (wave0 tail),
//  (2) VtK = V^T K via 4-wave j-split MFMA + LDS reduce.
// Phases are independent; carry loop overlaps other waves' MFMA.
// ---------------------------------------------------------------------------
__global__ __launch_bounds__(256) void scanvtk(
    const u16* __restrict__ ktg, const u16* __restrict__ vtg,
    float* __restrict__ Ctab, float* __restrict__ ksum, u16* __restrict__ vtk) {
  __shared__ float red[3][4096];      // vtk reduce; first 256 floats reused by scan
  const int t = threadIdx.x, l = t & 63, w = t >> 6;
  const int bh = blockIdx.x, h = bh & 7;
  const int lc = l & 15, lch = l >> 4;

  // ---- phase 1: K column sums ----
  {
    const int a = t & 63, q = t >> 6;
    const u16* kr = ktg + (size_t)bh * 64 * 2048 + (size_t)a * 2048 + q * 512;
    float s = 0.0f;
    for (int j = 0; j < 512; j += 8) {
      u16x8 v = *(const u16x8*)(kr + j);
      #pragma unroll
      for (int e = 0; e < 8; e++) s += bf2f(v[e]);
    }
    red[0][q * 64 + a] = s;
  }
  __syncthreads();
  if (t < 64) {
    ksum[bh * 64 + t] = red[0][t] + red[0][64 + t] + red[0][128 + t] + red[0][192 + t];
    const float gamma = 1.0f - exp2f(-5.0f - (float)h);
    const float g64 = exp2f(64.0f * log2f(gamma));
    float* Wp = Ctab + (size_t)bh * 32 * 64 + t;
    float C = 0.0f;
    for (int c = 0; c < 32; c++) {
      C = C * g64 + Wp[c * 64];
      Wp[c * 64] = C;
    }
  }
  // no barrier: red[0][0..255] is dead; vtk writes red only after its own
  // accumulation loop and a __syncthreads below.

  // ---- phase 2: VtK ----
  const u16* vb = vtg + (size_t)bh * 64 * 2048;
  const u16* kb = ktg + (size_t)bh * 64 * 2048;
  f32x4 acc[4][4] = {};
  for (int it = 0; it < 16; ++it) {
    const int j0 = w * 512 + it * 32 + lch * 8;
    bf16x8 af[4], bfr[4];
    #pragma unroll
    for (int mt = 0; mt < 4; mt++)
      af[mt] = *(const bf16x8*)(vb + (size_t)(mt * 16 + lc) * 2048 + j0);
    #pragma unroll
    for (int nt = 0; nt < 4; nt++)
      bfr[nt] = *(const bf16x8*)(kb + (size_t)(nt * 16 + lc) * 2048 + j0);
    #pragma unroll
    for (int mt = 0; mt < 4; mt++)
      #pragma unroll
      for (int nt = 0; nt < 4; nt++)
        acc[mt][nt] = MFMA16(af[mt], bfr[nt], acc[mt][nt]);
  }
  __syncthreads();   // scan fully done; red free for reduce
  if (w > 0) {
    #pragma unroll
    for (int mt = 0; mt < 4; mt++)
      #pragma unroll
      for (int nt = 0; nt < 4; nt++)
        #pragma unroll
        for (int r = 0; r < 4; r++)
          red[w - 1][(mt * 16 + lch * 4 + r) * 64 + nt * 16 + lc] = acc[mt][nt][r];
  }
  __syncthreads();
  if (w == 0) {
    u16* out = vtk + (size_t)bh * 64 * 64;
    #pragma unroll
    for (int mt = 0; mt < 4; mt++)
      #pragma unroll
      for (int nt = 0; nt < 4; nt++)
        #pragma unroll
        for (int r = 0; r < 4; r++) {
          int row = mt * 16 + lch * 4 + r, col = nt * 16 + lc;
          float v = acc[mt][nt][r] + red[0][row * 64 + col] + red[1][row * 64 + col] +
                    red[2][row * 64 + col];
          out[row * 64 + col] = f2bf(v);
        }
  }
}

// ---------------------------------------------------------------------------
// ret_out: o^T[b][i] = rrs_i*(L@V_chunk + gamma^(iloc+1)*C_{c-1}) + Q@VtK^T,
// den_i = q_i.Ksum + sqrt(rowsum_i); then /den, per-head LN, silu(g) gate.
// ---------------------------------------------------------------------------
__global__ __launch_bounds__(512) void ret_out(
    const u16* __restrict__ qkvg, const u16* __restrict__ vtg,
    const u16* __restrict__ vtk, const float* __restrict__ Ctab,
    const float* __restrict__ ksum, u16* __restrict__ gated) {
  const int S = 2048, DD = 2048;
  const int bh = blockIdx.x, b = bh >> 3, h = bh & 7;
  const int t = threadIdx.x, l = t & 63, w = t >> 6;
  const int lid = l & 31, hi = l >> 5;
  const int wrow = blockIdx.y * 256 + w * 32;
  const int i_q = wrow + lid;
  const int chunk = wrow >> 6;          // wave-uniform
  const int iloc = i_q & 63;

  __shared__ __align__(16) u16 sm[18432];
  float* smf = (float*)sm;

  const size_t base = (size_t)b * S * DD + (size_t)h * 64;
  const u16* qp = qkvg + base;
  const u16* gp = qkvg + base + 1536;

  const float gamma = 1.0f - exp2f(-5.0f - (float)h);
  const float l2g = log2f(gamma);
  const float rowsum = (1.0f - exp2f((float)(i_q + 1) * l2g)) * exp2f(5.0f + (float)h);
  const float rrs = rsqrtf(rowsum);

  // generate L (lower-tri gamma^(iloc-jloc), bf16) into LDS
  {
    const int il = t >> 3, j0 = (t & 7) * 8;
    u16x8 row;
    #pragma unroll
    for (int e = 0; e < 8; e++) {
      int d = il - (j0 + e);
      row[e] = (d >= 0) ? f2bf(exp2f((float)d * l2g)) : (u16)0;
    }
    *(u16x8*)&sm[il * 72 + j0] = row;
  }
  // stage carries (chunks by*4-1 .. by*4+2) and Ksum
  if (t < 256) {
    int cc = blockIdx.y * 4 - 1 + (t >> 6);
    smf[4608 + t] = (cc >= 0) ? Ctab[((size_t)bh * 32 + cc) * 64 + (t & 63)] : 0.0f;
  } else if (t < 320) {
    smf[4864 + (t - 256)] = ksum[bh * 64 + (t - 256)];
  }
  __syncthreads();

  bf16x8 qf[4];
  #pragma unroll
  for (int kc = 0; kc < 4; kc++)
    qf[kc] = *(const bf16x8*)(qp + (size_t)i_q * DD + kc * 16 + 8 * hi);

  const u16* vt_b = vtg + (size_t)bh * 64 * S;
  const u16* vk_b = vtk + (size_t)bh * 64 * 64;

  f32x16 accO0, accO1;
  #pragma unroll
  for (int r = 0; r < 16; r++) { accO0[r] = 0.0f; accO1[r] = 0.0f; }

  // 1) L @ V_chunk
  #pragma unroll
  for (int kc = 0; kc < 4; kc++) {
    bf16x8 lb = *(const bf16x8*)&sm[iloc * 72 + kc * 16 + hi * 8];
    bf16x8 va0 = *(const bf16x8*)(vt_b + (size_t)lid * S + chunk * 64 + kc * 16 + hi * 8);
    bf16x8 va1 = *(const bf16x8*)(vt_b + (size_t)(lid + 32) * S + chunk * 64 + kc * 16 + hi * 8);
    accO0 = MFMA32(va0, lb, accO0);
    accO1 = MFMA32(va1, lb, accO1);
  }
  // 2) carry
  {
    const float gpw = exp2f((float)(iloc + 1) * l2g);
    const float* Cst = &smf[4608 + (w >> 1) * 64];
    #pragma unroll
    for (int r = 0; r < 16; r++) {
      int br = (r & 3) + 8 * (r >> 2) + 4 * hi;
      accO0[r] += gpw * Cst[br];
      accO1[r] += gpw * Cst[32 + br];
    }
  }
  // 3) scale decay part by rrs
  #pragma unroll
  for (int r = 0; r < 16; r++) { accO0[r] *= rrs; accO1[r] *= rrs; }
  // 4) Q @ VtK^T
  #pragma unroll
  for (int kc = 0; kc < 4; kc++) {
    bf16x8 ka0 = *(const bf16x8*)(vk_b + (size_t)lid * 64 + kc * 16 + hi * 8);
    bf16x8 ka1 = *(const bf16x8*)(vk_b + (size_t)(lid + 32) * 64 + kc * 16 + hi * 8);
    accO0 = MFMA32(ka0, qf[kc], accO0);
    accO1 = MFMA32(ka1, qf[kc], accO1);
  }
  // 5) den
  float dsum = 0.0f;
  #pragma unroll
  for (int kc = 0; kc < 4; kc++) {
    const float* Ks = &smf[4864 + kc * 16 + hi * 8];
    #pragma unroll
    for (int e = 0; e < 8; e++) dsum += bfel(qf[kc], e) * Ks[e];
  }
  dsum += __shfl_xor(dsum, 32);
  float den = dsum + sqrtf(rowsum);
  float rden = 1.0f / fmaxf(fabsf(den), 1.0f);

  // 6) normalize + per-head LN
  float o0[16], o1[16];
  float s1 = 0.0f, s2 = 0.0f;
  #pragma unroll
  for (int r = 0; r < 16; r++) {
    o0[r] = accO0[r] * rden; s1 += o0[r]; s2 += o0[r] * o0[r];
    o1[r] = accO1[r] * rden; s1 += o1[r]; s2 += o1[r] * o1[r];
  }
  s1 += __shfl_xor(s1, 32);
  s2 += __shfl_xor(s2, 32);
  float mu = s1 * (1.0f / 64.0f);
  float var = s2 * (1.0f / 64.0f) - mu * mu;
  float rv = rsqrtf(var + 1e-6f);

  __syncthreads();   // all waves done with L/Ct/Ksum regions

  u16* Ot = sm + w * 2304;
  #pragma unroll
  for (int r = 0; r < 16; r++) {
    int d = (r & 3) + 8 * (r >> 2) + 4 * hi;
    Ot[lid * 72 + d]      = f2bf((o0[r] - mu) * rv);
    Ot[lid * 72 + 32 + d] = f2bf((o1[r] - mu) * rv);
  }
  {
    const int i2 = l >> 1, half = l & 1;
    const int row = wrow + i2;
    #pragma unroll
    for (int c = 0; c < 4; c++) {
      u16x8 y8 = *(const u16x8*)&Ot[i2 * 72 + half * 32 + c * 8];
      u16x8 g8 = *(const u16x8*)(gp + (size_t)row * DD + half * 32 + c * 8);
      u16x8 o8;
      #pragma unroll
      for (int e = 0; e < 8; e++) {
        float gv = bf2f(g8[e]);
        float sg = gv / (1.0f + __expf(-gv));
        o8[e] = f2bf(bf2f(y8[e]) * sg);
      }
      *(u16x8*)&gated[((size_t)(b * S + row)) * 512 + h * 64 + half * 32 + c * 8] = o8;
    }
  }
}

// ---------------------------------------------------------------------------
// add_lnT: y = LN(A + B) over D=512; A fp32 (AF32=1) or bf16 (AF32=0),
// B bf16. Writes fp32 (WF=1) and/or bf16 (Ob != null). One wave per row.
// ---------------------------------------------------------------------------
template <int AF32, int WF>
__global__ __launch_bounds__(256) void add_lnT(
    const void* __restrict__ Ap, const u16* __restrict__ Bv,
    const float* __restrict__ gam, const float* __restrict__ bet, float eps,
    float* __restrict__ Of, u16* __restrict__ Ob) {
  int row = blockIdx.x * 4 + (threadIdx.x >> 6);
  int l = threadIdx.x & 63;
  float x[8];
  u16x8 cv = *(const u16x8*)(Bv + (size_t)row * 512 + l * 8);
  if (AF32) {
    const float* a = (const float*)Ap + (size_t)row * 512 + l * 8;
    f32x4 a0 = *(const f32x4*)a, a1 = *(const f32x4*)(a + 4);
    #pragma unroll
    for (int e = 0; e < 4; e++) { x[e] = a0[e] + bf2f(cv[e]); x[4 + e] = a1[e] + bf2f(cv[4 + e]); }
  } else {
    u16x8 av = *(const u16x8*)((const u16*)Ap + (size_t)row * 512 + l * 8);
    #pragma unroll
    for (int e = 0; e < 8; e++) x[e] = bf2f(av[e]) + bf2f(cv[e]);
  }
  float s = 0.f, s2 = 0.f;
  #pragma unroll
  for (int e = 0; e < 8; e++) { s += x[e]; s2 += x[e] * x[e]; }
  #pragma unroll
  for (int m = 1; m <= 32; m <<= 1) { s += __shfl_xor(s, m); s2 += __shfl_xor(s2, m); }
  float mu = s * (1.0f / 512.0f);
  float var = s2 * (1.0f / 512.0f) - mu * mu;
  float rinv = rsqrtf(var + eps);
  f32x4 g0 = *(const f32x4*)(gam + l * 8), g1 = *(const f32x4*)(gam + l * 8 + 4);
  f32x4 b0 = *(const f32x4*)(bet + l * 8), b1 = *(const f32x4*)(bet + l * 8 + 4);
  f32x4 y0, y1;
  #pragma unroll
  for (int e = 0; e < 4; e++) {
    y0[e] = (x[e] - mu) * rinv * g0[e] + b0[e];
    y1[e] = (x[4 + e] - mu) * rinv * g1[e] + b1[e];
  }
  if (WF) {
    float* op = Of + (size_t)row * 512 + l * 8;
    *(f32x4*)op = y0;
    *(f32x4*)(op + 4) = y1;
  }
  if (Ob) {
    u16x8 rb_;
    #pragma unroll
    for (int e = 0; e < 4; e++) { rb_[e] = f2bf(y0[e]); rb_[4 + e] = f2bf(y1[e]); }
    *(u16x8*)(Ob + (size_t)row * 512 + l * 8) = rb_;
  }
}

// ---------------------------------------------------------------------------
// In-place sub-LN over FFN=2048 (bf16), eps 1e-6, affine. One wave per row.
// ---------------------------------------------------------------------------
__global__ __launch_bounds__(256) void subln_ffn(
    u16* __restrict__ hbuf, const float* __restrict__ gam, const float* __restrict__ bet) {
  int row = blockIdx.x * 4 + (threadIdx.x >> 6);
  int l = threadIdx.x & 63;
  u16* p = hbuf + (size_t)row * 2048;
  float x[32];
  #pragma unroll
  for (int cch = 0; cch < 4; cch++) {
    u16x8 v = *(const u16x8*)(p + cch * 512 + l * 8);
    #pragma unroll
    for (int e = 0; e < 8; e++) x[cch * 8 + e] = bf2f(v[e]);
  }
  float s = 0.f, s2 = 0.f;
  #pragma unroll
  for (int e = 0; e < 32; e++) { s += x[e]; s2 += x[e] * x[e]; }
  #pragma unroll
  for (int m = 1; m <= 32; m <<= 1) { s += __shfl_xor(s, m); s2 += __shfl_xor(s2, m); }
  float mu = s * (1.0f / 2048.0f);
  float var = s2 * (1.0f / 2048.0f) - mu * mu;
  float rinv = rsqrtf(var + 1e-6f);
  #pragma unroll
  for (int cch = 0; cch < 4; cch++) {
    int col = cch * 512 + l * 8;
    f32x4 g0 = *(const f32x4*)(gam + col), g1 = *(const f32x4*)(gam + col + 4);
    f32x4 b0 = *(const f32x4*)(bet + col), b1 = *(const f32x4*)(bet + col + 4);
    u16x8 o;
    #pragma unroll
    for (int e = 0; e < 4; e++) {
      o[e]     = f2bf((x[cch * 8 + e]     - mu) * rinv * g0[e] + b0[e]);
      o[4 + e] = f2bf((x[cch * 8 + 4 + e] - mu) * rinv * g1[e] + b1[e]);
    }
    *(u16x8*)(p + col) = o;
  }
}

// ---------------------------------------------------------------------------
extern "C" void kernel_launch(void* const* d_in, const int* in_sizes, int n_in,
                              void* d_out, int out_size, void* d_ws, size_t ws_size,
                              hipStream_t stream) {
  const float* src  = (const float*)d_in[0];
  const float* wq   = (const float*)d_in[3];
  const float* bq   = (const float*)d_in[4];
  const float* wk   = (const float*)d_in[5];
  const float* bk   = (const float*)d_in[6];
  const float* wv   = (const float*)d_in[7];
  const float* bv   = (const float*)d_in[8];
  const float* wg   = (const float*)d_in[9];
  const float* bg   = (const float*)d_in[10];
  const float* wo   = (const float*)d_in[11];
  const float* bo   = (const float*)d_in[12];
  const float* fc1w = (const float*)d_in[13];
  const float* fc1b = (const float*)d_in[14];
  const float* fc2w = (const float*)d_in[15];
  const float* fc2b = (const float*)d_in[16];
  const float* lng  = (const float*)d_in[17];
  const float* lnb  = (const float*)d_in[18];
  const float* n0g  = (const float*)d_in[19];
  const float* n0b  = (const float*)d_in[20];
  const float* n1g  = (const float*)d_in[21];
  const float* n1b  = (const float*)d_in[22];

  if (ws_size < 91242496u) return;  // need ~91.3 MB scratch

  char* ws = (char*)d_ws;
  u16*   src_bf = (u16*)(ws + 0);
  u16*   Wcat   = (u16*)(ws + 8388608);
  u16*   wo_bf  = (u16*)(ws + 10485760);
  u16*   fc1_bf = (u16*)(ws + 11010048);
  u16*   fc2_bf = (u16*)(ws + 13107200);
  float* bcat   = (float*)(ws + 15204352);
  u16*   qkvg   = (u16*)(ws + 15212544);   // 32 MB; reused as h1 after retention
  u16*   gated  = (u16*)(ws + 48766976);   // 8 MB
  u16*   attn   = (u16*)(ws + 57155584);   // 8 MB; reused as y (fc2 out)
  u16*   vtg    = (u16*)(ws + 65544192);   // 8 MB
  u16*   ktg    = (u16*)(ws + 73932800);   // 8 MB
  u16*   xbf    = (u16*)(ws + 82321408);   // 8 MB
  float* Ctab   = (float*)(ws + 90710016); // 256 KB (W then carries, in place)
  u16*   vtkb   = (u16*)(ws + 90972160);   // 256 KB
  float* ksumb  = (float*)(ws + 91234304); // 8 KB

  // 1. casts / weight concat
  prep_cast<<<3713, 256, 0, stream>>>(src, wq, wk, wv, wg, wo, fc1w, fc2w,
                                      bq, bk, bv, bg,
                                      src_bf, Wcat, wo_bf, fc1_bf, fc2_bf, bcat);
  // 2. QKVG projection: (8192x512) @ (2048x512)^T
  gemm_v3<0><<<1024, 256, 0, stream>>>(src_bf, Wcat, bcat, qkvg, 2048, 512, 16);
  // 3. transpose K,V (+ per-chunk decay sums W)
  transkv<<<dim3(32, 32), 256, 0, stream>>>(qkvg, ktg, vtg, Ctab);
  // 4. merged: Ksum + carry scan + VtK
  scanvtk<<<32, 256, 0, stream>>>(ktg, vtg, Ctab, ksumb, vtkb);
  // 5. retention output + per-head LN + silu gating
  ret_out<<<dim3(32, 8), 512, 0, stream>>>(qkvg, vtg, vtkb, Ctab, ksumb, gated);
  // 6. output projection (8192x512 @ 512x512^T)
  gemm_m64<0><<<512, 256, 0, stream>>>(gated, wo_bf, bo, attn, 512, 512, 4);
  // 7. x = LN(src + attn), n0, eps 1e-5 -> bf16 only
  add_lnT<1, 0><<<2048, 256, 0, stream>>>(src, attn, n0g, n0b, 1e-5f, nullptr, xbf);
  // 8. fc1 + exact gelu -> h1 (aliases qkvg)
  gemm_v3<1><<<1024, 256, 0, stream>>>(xbf, fc1_bf, fc1b, qkvg, 2048, 512, 16);
  // 9. sub-LN over 2048 (in place)
  subln_ffn<<<2048, 256, 0, stream>>>(qkvg, lng, lnb);
  // 10. fc2 -> y (aliases attn)
  gemm_m64<0><<<512, 256, 0, stream>>>(qkvg, fc2_bf, fc2b, attn, 512, 2048, 4);
  // 11. out = LN(x + y), n1, eps 1e-5 -> d_out (fp32)
  add_lnT<0, 1><<<2048, 256, 0, stream>>>(xbf, attn, n1g, n1b, 1e-5f, (float*)d_out, nullptr);
}